// Round 1
// baseline (1482.701 us; speedup 1.0000x reference)
//
#include <hip/hip_runtime.h>
#include <math.h>
#include <stdint.h>

typedef unsigned long long u64;
typedef unsigned int u32;

#define NB 8
#define NA 76725
#define NC 80
#define KC 256
#define MAXT 200
#define CAP 4096
#define SORTN 1024
#define TAU 2.0f

// Workspace layout (bytes). Total ~25.0 MB.
#define OFF_BUFA      0ull            // u64 [NB*NC*CAP]   20,971,520
#define OFF_CLASSLIST 20971520ull     // u64 [NB*NC*KC]     1,310,720
#define OFF_C1        22282240ull     // u64 [NB*8*KC]        131,072
#define OFF_CANDBOX   22413312ull     // float4[NB*NC*KC]   2,621,440
#define OFF_COUNTS    25034752ull     // u32 [NB*NC]            2,560

// ---------------------------------------------------------------------------
// Kernel A: stream cls_pred (float4, coalesced), append logits > TAU to
// per-(b,c) buffers. Entry = (logit_bits << 32) | anchor_index.
// ---------------------------------------------------------------------------
__global__ __launch_bounds__(256) void kfilter(const float* __restrict__ cls,
                                               u64* __restrict__ bufA,
                                               u32* __restrict__ counts) {
  const float4* p = (const float4*)cls;
  const int n4 = NB * NA * NC / 4;       // 12,276,000
  const int perB = NA * NC / 4;          // 1,534,500
  for (int i = blockIdx.x * blockDim.x + threadIdx.x; i < n4;
       i += gridDim.x * blockDim.x) {
    float4 v = p[i];
    int b = i / perB;
    int r = i - b * perB;
    int a = r / (NC / 4);
    int c0 = (r - a * (NC / 4)) * 4;
    float vv[4] = {v.x, v.y, v.z, v.w};
#pragma unroll
    for (int j = 0; j < 4; j++) {
      float x = vv[j];
      if (x > TAU) {
        int bc = b * NC + c0 + j;
        u32 pos = atomicAdd(&counts[bc], 1u);
        if (pos < CAP)
          bufA[(size_t)bc * CAP + pos] =
              ((u64)__float_as_uint(x) << 32) | (u32)a;
      }
    }
  }
}

// ---------------------------------------------------------------------------
// Kernel B: per-(b,c) block. Histogram-select ~top-256 region, sort by
// (sigmoid score desc, anchor asc), decode boxes, greedy NMS (wave 0, shfl),
// cap 200, write compacted sorted kept list + candidate boxes.
// ---------------------------------------------------------------------------
__global__ __launch_bounds__(256) void kselect(
    const float* __restrict__ cls, const float* __restrict__ boxp,
    const float* __restrict__ anc, u64* __restrict__ bufA,
    const u32* __restrict__ counts, u64* __restrict__ classList,
    float4* __restrict__ candBox) {
  __shared__ u32 hist[1024];
  __shared__ int sbsum[64];
  __shared__ int sT, sNsel, sExtra;
  __shared__ u64 skey[SORTN];
  __shared__ float4 sBox[KC];
  __shared__ int sElig[KC];

  const int tid = threadIdx.x;
  const int bc = blockIdx.x;
  const int b = bc / NC, c = bc % NC;
  u64* buf = bufA + (size_t)bc * CAP;

  int cnt0 = (int)counts[bc];
  int cnt = cnt0;
  if (cnt0 < KC) {
    // Fallback (never expected on this data): collect 0 < logit <= TAU too.
    if (tid == 0) sExtra = 0;
    __syncthreads();
    for (int a = tid; a < NA; a += 256) {
      float x = cls[((size_t)b * NA + a) * NC + c];
      if (x > 0.0f && !(x > TAU)) {
        int pos = cnt0 + atomicAdd(&sExtra, 1);
        if (pos < CAP) buf[pos] = ((u64)__float_as_uint(x) << 32) | (u32)a;
      }
    }
    __syncthreads();
    cnt = cnt0 + sExtra;
  }
  if (cnt > CAP) cnt = CAP;

  // --- histogram over logit (bin width 1/170, covers (0, 6.02]) ---
  for (int i = tid; i < 1024; i += 256) hist[i] = 0;
  if (tid == 0) sNsel = 0;
  __syncthreads();
  for (int e = tid; e < cnt; e += 256) {
    float f = __uint_as_float((u32)(buf[e] >> 32));
    int bin = (int)(f * 170.0f);
    bin = bin < 0 ? 0 : (bin > 1023 ? 1023 : bin);
    atomicAdd(&hist[bin], 1u);
  }
  __syncthreads();
  if (tid < 64) {
    int s = 0;
    for (int i = 0; i < 16; i++) s += (int)hist[tid * 16 + i];
    sbsum[tid] = s;
  }
  __syncthreads();
  if (tid == 0) {
    // Find largest bin T with suffix-count(bins >= T) >= KC (or 0).
    int acc = 0, sb = 63;
    while (sb >= 0 && acc + sbsum[sb] < KC) { acc += sbsum[sb]; sb--; }
    int T = 0;
    if (sb >= 0) {
      int bin = sb * 16 + 15;
      while (bin > sb * 16 && acc + (int)hist[bin] < KC) {
        acc += (int)hist[bin];
        bin--;
      }
      T = bin;
    }
    sT = T;
  }
  __syncthreads();
  const int T = sT;

  // --- compact selected entries with final sort key ---
  for (int e = tid; e < cnt; e += 256) {
    u64 k = buf[e];
    float f = __uint_as_float((u32)(k >> 32));
    int bin = (int)(f * 170.0f);
    bin = bin < 0 ? 0 : (bin > 1023 ? 1023 : bin);
    if (bin >= T) {
      float sc = 1.0f / (1.0f + expf(-f));   // f32 sigmoid, matches ref order
      u32 a = (u32)k;
      int pos = atomicAdd(&sNsel, 1);
      if (pos < SORTN)
        skey[pos] = ((u64)__float_as_uint(sc) << 32) | (0xFFFFFFFFu - a);
    }
  }
  __syncthreads();
  int nsel = sNsel;
  if (nsel > SORTN) nsel = SORTN;
  for (int i = tid; i < SORTN; i += 256)
    if (i >= nsel) skey[i] = 0;
  __syncthreads();

  // --- bitonic sort, descending (value desc, index asc via ~a) ---
  for (int k = 2; k <= SORTN; k <<= 1) {
    for (int j = k >> 1; j > 0; j >>= 1) {
      for (int t = tid; t < SORTN / 2; t += 256) {
        int i = ((t & ~(j - 1)) << 1) | (t & (j - 1));
        int ixj = i | j;
        u64 x = skey[i], y = skey[ixj];
        bool desc = ((i & k) == 0);
        if (desc ? (x < y) : (x > y)) { skey[i] = y; skey[ixj] = x; }
      }
      __syncthreads();
    }
  }

  // --- decode top-256 boxes (no-FMA f32 ops to mirror separate mul/add) ---
  {
    u64 k = skey[tid];
    float sc = __uint_as_float((u32)(k >> 32));
    u32 a = 0xFFFFFFFFu - (u32)k;
    int el = (k != 0ull) && (sc > 0.5f);
    if (!el || a >= NA) a = 0;   // padding guard (box masked out downstream)
    float4 p = ((const float4*)boxp)[(size_t)b * NA + a];
    float4 an = ((const float4*)anc)[a];
    float dx = __fmul_rn(p.x, 0.1f), dy = __fmul_rn(p.y, 0.1f);
    float dw = __fmul_rn(p.z, 0.2f), dh = __fmul_rn(p.w, 0.2f);
    float cx = __fadd_rn(__fmul_rn(dx, an.z), an.x);
    float cy = __fadd_rn(__fmul_rn(dy, an.w), an.y);
    float w = __fmul_rn(expf(dw), an.z);
    float h = __fmul_rn(expf(dh), an.w);
    float4 bx;
    bx.x = __fsub_rn(cx, __fmul_rn(0.5f, w));
    bx.y = __fsub_rn(cy, __fmul_rn(0.5f, h));
    bx.z = __fadd_rn(cx, __fmul_rn(0.5f, w));
    bx.w = __fadd_rn(cy, __fmul_rn(0.5f, h));
    sBox[tid] = bx;
    sElig[tid] = el;
    candBox[(size_t)bc * KC + tid] = bx;
  }
  __syncthreads();

  // --- greedy NMS on wave 0: lane ln owns candidates s*64+ln ---
  if (tid < 64) {
    const int ln = tid;
    float x1[4], y1[4], x2[4], y2[4], ar[4];
    int keep = 0;
#pragma unroll
    for (int s = 0; s < 4; s++) {
      int j = s * 64 + ln;
      float4 bj = sBox[j];
      x1[s] = bj.x; y1[s] = bj.y; x2[s] = bj.z; y2[s] = bj.w;
      ar[s] = __fmul_rn(__fsub_rn(bj.z, bj.x), __fsub_rn(bj.w, bj.y));
      if (sElig[j]) keep |= (1 << s);
    }
    for (int i = 0; i < KC; i++) {
      int ki = __shfl(keep, i & 63, 64);
      if ((ki >> (i >> 6)) & 1) {          // wave-uniform branch
        float4 bi = sBox[i];               // same-address LDS broadcast
        float ai = __fmul_rn(__fsub_rn(bi.z, bi.x), __fsub_rn(bi.w, bi.y));
#pragma unroll
        for (int s = 0; s < 4; s++) {
          int j = s * 64 + ln;
          if (j > i) {
            float lx = fmaxf(bi.x, x1[s]), ly = fmaxf(bi.y, y1[s]);
            float rx = fminf(bi.z, x2[s]), ry = fminf(bi.w, y2[s]);
            float wx = fmaxf(__fsub_rn(rx, lx), 0.0f);
            float wy = fmaxf(__fsub_rn(ry, ly), 0.0f);
            float inter = __fmul_rn(wx, wy);
            float uni = fmaxf(__fsub_rn(__fadd_rn(ai, ar[s]), inter), 1e-8f);
            float iou = __fdiv_rn(inter, uni);
            if (iou > 0.5f) keep &= ~(1 << s);
          }
        }
      }
    }
    // cap at MAXT kept (cumsum over pre-cap keep), compact in order
    u64 m[4];
#pragma unroll
    for (int s = 0; s < 4; s++) m[s] = __ballot((keep >> s) & 1);
    int tot = 0;
#pragma unroll
    for (int s = 0; s < 4; s++) tot += __popcll(m[s]);
    int keptTotal = tot < MAXT ? tot : MAXT;
    u64 lmask = (1ull << ln) - 1ull;
    int base = 0;
#pragma unroll
    for (int s = 0; s < 4; s++) {
      int j = s * 64 + ln;
      int cum = base + (int)__popcll(m[s] & lmask);
      if (((keep >> s) & 1) && cum < MAXT) {
        u64 hi = skey[j] >> 32;
        classList[(size_t)bc * KC + cum] =
            (hi << 32) | (u64)(0xFFFFFFFFu - (u32)(c * KC + j));
      }
      base += (int)__popcll(m[s]);
    }
    for (int t2 = ln; t2 < KC; t2 += 64)
      if (t2 >= keptTotal) classList[(size_t)bc * KC + t2] = 0;
  }
}

// ---------------------------------------------------------------------------
// Top-256 merge of two desc-sorted 256-lists: half-cleaner + bitonic clean.
// ---------------------------------------------------------------------------
__device__ __forceinline__ void merge_step(u64* acc, const u64* cur, int t) {
  u64 x = acc[t], y = cur[KC - 1 - t];
  acc[t] = x > y ? x : y;          // each thread touches only acc[t]
  __syncthreads();
  for (int s = 128; s >= 1; s >>= 1) {
    if (t < 128) {
      int i = ((t & ~(s - 1)) << 1) | (t & (s - 1));
      u64 a = acc[i], b = acc[i + s];
      if (a < b) { acc[i] = b; acc[i + s] = a; }
    }
    __syncthreads();
  }
}

__global__ __launch_bounds__(256) void kmerge1(const u64* __restrict__ classList,
                                               u64* __restrict__ c1) {
  __shared__ u64 acc[KC], cur[KC];
  int t = threadIdx.x;
  int b = blockIdx.x >> 3, g = blockIdx.x & 7;
  const u64* base = classList + (size_t)(b * NC + g * 10) * KC;
  acc[t] = base[t];
  __syncthreads();
  for (int m = 1; m < 10; m++) {
    cur[t] = base[(size_t)m * KC + t];
    __syncthreads();
    merge_step(acc, cur, t);
  }
  c1[(size_t)blockIdx.x * KC + t] = acc[t];
}

__global__ __launch_bounds__(256) void kmerge2(const u64* __restrict__ c1,
                                               const float4* __restrict__ candBox,
                                               float* __restrict__ out) {
  __shared__ u64 acc[KC], cur[KC];
  int t = threadIdx.x, b = blockIdx.x;
  const u64* base = c1 + (size_t)b * 8 * KC;
  acc[t] = base[t];
  __syncthreads();
  for (int m = 1; m < 8; m++) {
    cur[t] = base[(size_t)m * KC + t];
    __syncthreads();
    merge_step(acc, cur, t);
  }
  if (t < MAXT) {
    u64 k = acc[t];
    float4 bx = make_float4(0.f, 0.f, 0.f, 0.f);
    float sc = 0.0f, lb = -1.0f;
    if (k != 0ull) {
      sc = __uint_as_float((u32)(k >> 32));
      u32 flat = 0xFFFFFFFFu - (u32)k;
      int cc = (int)(flat >> 8), kk = (int)(flat & 255u);
      bx = candBox[((size_t)b * NC + cc) * KC + kk];
      lb = (float)cc;
    }
    float* ob = out + ((size_t)b * MAXT + t) * 4;
    ob[0] = bx.x; ob[1] = bx.y; ob[2] = bx.z; ob[3] = bx.w;
    out[NB * MAXT * 4 + b * MAXT + t] = sc;                 // scores @ 6400
    out[NB * MAXT * 4 + NB * MAXT + b * MAXT + t] = lb;     // labels @ 8000
  }
}

extern "C" void kernel_launch(void* const* d_in, const int* in_sizes, int n_in,
                              void* d_out, int out_size, void* d_ws,
                              size_t ws_size, hipStream_t stream) {
  const float* boxp = (const float*)d_in[0];   // [B,A,4]
  const float* cls = (const float*)d_in[1];    // [B,A,C]
  const float* anc = (const float*)d_in[2];    // [A,4]
  char* ws = (char*)d_ws;
  u64* bufA = (u64*)(ws + OFF_BUFA);
  u64* classList = (u64*)(ws + OFF_CLASSLIST);
  u64* c1 = (u64*)(ws + OFF_C1);
  float4* candBox = (float4*)(ws + OFF_CANDBOX);
  u32* counts = (u32*)(ws + OFF_COUNTS);

  hipMemsetAsync(counts, 0, NB * NC * sizeof(u32), stream);
  kfilter<<<4096, 256, 0, stream>>>(cls, bufA, counts);
  kselect<<<NB * NC, 256, 0, stream>>>(cls, boxp, anc, bufA, counts, classList,
                                       candBox);
  kmerge1<<<NB * 8, 256, 0, stream>>>(classList, c1);
  kmerge2<<<NB, 256, 0, stream>>>(c1, candBox, (float*)d_out);
}

// Round 2
// 433.978 us; speedup vs baseline: 3.4165x; 3.4165x over previous
//
#include <hip/hip_runtime.h>
#include <math.h>
#include <stdint.h>

typedef unsigned long long u64;
typedef unsigned int u32;

#define NB 8
#define NA 76725
#define NC 80
#define KC 256
#define MAXT 200
#define CAP 2048
#define SORTN 1024
#define TAU 2.0f
#define CHUNK 1024
#define NCHUNK 75          // ceil(76725/1024)
#define BCAP 64            // per-class per-block LDS bucket capacity (~23 exp, 8.5 sigma)
#define CSTRIDE 16         // counts padded to one per 64B line

// Workspace layout (bytes). Total ~14.6 MB (previous 25 MB footprint passed).
#define OFF_BUFA      0ull            // u64 [NB*NC*CAP]   10,485,760
#define OFF_CLASSLIST 10485760ull     // u64 [NB*NC*KC]     1,310,720
#define OFF_C1        11796480ull     // u64 [NB*8*KC]        131,072
#define OFF_CANDBOX   11927552ull     // float4[NB*NC*KC]   2,621,440
#define OFF_COUNTS    14548992ull     // u32 [NB*NC*CSTRIDE]   40,960

// ---------------------------------------------------------------------------
// Kernel A: each block owns a [1024-anchor x 80-class] tile. Candidates
// (logit > TAU) go to per-class LDS buckets; one global atomicAdd per class
// per block reserves a contiguous range in bufA; cooperative flush.
// Entry = (logit_bits << 32) | anchor_index.
// ---------------------------------------------------------------------------
__global__ __launch_bounds__(256) void kfilter(const float* __restrict__ cls,
                                               u64* __restrict__ bufA,
                                               u32* __restrict__ counts) {
  __shared__ u64 bucket[NC][BCAP];   // 40 KB
  __shared__ u32 bcnt[NC];
  __shared__ u32 gbase[NC];
  __shared__ u32 pref[NC + 1];

  const int b = blockIdx.x / NCHUNK;
  const int ch = blockIdx.x % NCHUNK;
  const int tid = threadIdx.x;
  const int a0 = ch * CHUNK;
  const int aN = (NA - a0) < CHUNK ? (NA - a0) : CHUNK;

  for (int i = tid; i < NC; i += 256) bcnt[i] = 0;
  __syncthreads();

  // Tile is contiguous: cls[b, a0:a0+aN, :]; NC/4 = 20 float4 per anchor.
  const float4* p = (const float4*)(cls + ((size_t)b * NA + a0) * NC);
  const int n4 = aN * (NC / 4);
  for (int i = tid; i < n4; i += 256) {
    float4 v = p[i];
    int a = a0 + i / (NC / 4);
    int c0 = (i % (NC / 4)) * 4;
    float vv[4] = {v.x, v.y, v.z, v.w};
#pragma unroll
    for (int j = 0; j < 4; j++) {
      if (vv[j] > TAU) {
        int c = c0 + j;
        u32 pos = atomicAdd(&bcnt[c], 1u);
        if (pos < BCAP)
          bucket[c][pos] = ((u64)__float_as_uint(vv[j]) << 32) | (u32)a;
      }
    }
  }
  __syncthreads();
  if (tid < NC) {
    u32 n = bcnt[tid];
    if (n > BCAP) n = BCAP;
    bcnt[tid] = n;
    gbase[tid] = atomicAdd(&counts[(b * NC + tid) * CSTRIDE], n);
  }
  __syncthreads();
  if (tid == 0) {
    u32 s = 0;
    for (int c = 0; c < NC; c++) { pref[c] = s; s += bcnt[c]; }
    pref[NC] = s;
  }
  __syncthreads();
  const int total = (int)pref[NC];
  for (int e = tid; e < total; e += 256) {
    int lo = 0, hi = NC;                   // binary search: pref[lo] <= e < pref[lo+1]
    while (lo + 1 < hi) { int mid = (lo + hi) >> 1; if ((int)pref[mid] <= e) lo = mid; else hi = mid; }
    int c = lo;
    int loc = e - (int)pref[c];
    u32 gb = gbase[c] + (u32)loc;
    if (gb < CAP)
      bufA[((size_t)(b * NC + c)) * CAP + gb] = bucket[c][loc];
  }
}

// ---------------------------------------------------------------------------
// Kernel B: per-(b,c) block. Histogram-select ~top-256 region, sort by
// (sigmoid score desc, anchor asc), decode boxes, greedy NMS (wave 0, shfl),
// cap 200, write compacted sorted kept list + candidate boxes.
// ---------------------------------------------------------------------------
__global__ __launch_bounds__(256) void kselect(
    const float* __restrict__ cls, const float* __restrict__ boxp,
    const float* __restrict__ anc, u64* __restrict__ bufA,
    const u32* __restrict__ counts, u64* __restrict__ classList,
    float4* __restrict__ candBox) {
  __shared__ u32 hist[1024];
  __shared__ int sbsum[64];
  __shared__ int sT, sNsel, sExtra;
  __shared__ u64 skey[SORTN];
  __shared__ float4 sBox[KC];
  __shared__ int sElig[KC];

  const int tid = threadIdx.x;
  const int bc = blockIdx.x;
  const int b = bc / NC, c = bc % NC;
  u64* buf = bufA + (size_t)bc * CAP;

  int cnt0 = (int)counts[bc * CSTRIDE];
  if (cnt0 > CAP) cnt0 = CAP;
  int cnt = cnt0;
  if (cnt0 < KC) {
    // Fallback (never expected on this data): collect 0 < logit <= TAU too.
    if (tid == 0) sExtra = 0;
    __syncthreads();
    for (int a = tid; a < NA; a += 256) {
      float x = cls[((size_t)b * NA + a) * NC + c];
      if (x > 0.0f && !(x > TAU)) {
        int pos = cnt0 + atomicAdd(&sExtra, 1);
        if (pos < CAP) buf[pos] = ((u64)__float_as_uint(x) << 32) | (u32)a;
      }
    }
    __syncthreads();
    cnt = cnt0 + sExtra;
  }
  if (cnt > CAP) cnt = CAP;

  // --- histogram over logit (bin width 1/170, covers (0, 6.02]) ---
  for (int i = tid; i < 1024; i += 256) hist[i] = 0;
  if (tid == 0) sNsel = 0;
  __syncthreads();
  for (int e = tid; e < cnt; e += 256) {
    float f = __uint_as_float((u32)(buf[e] >> 32));
    int bin = (int)(f * 170.0f);
    bin = bin < 0 ? 0 : (bin > 1023 ? 1023 : bin);
    atomicAdd(&hist[bin], 1u);
  }
  __syncthreads();
  if (tid < 64) {
    int s = 0;
    for (int i = 0; i < 16; i++) s += (int)hist[tid * 16 + i];
    sbsum[tid] = s;
  }
  __syncthreads();
  if (tid == 0) {
    int acc = 0, sb = 63;
    while (sb >= 0 && acc + sbsum[sb] < KC) { acc += sbsum[sb]; sb--; }
    int T = 0;
    if (sb >= 0) {
      int bin = sb * 16 + 15;
      while (bin > sb * 16 && acc + (int)hist[bin] < KC) {
        acc += (int)hist[bin];
        bin--;
      }
      T = bin;
    }
    sT = T;
  }
  __syncthreads();
  const int T = sT;

  // --- compact selected entries with final sort key ---
  for (int e = tid; e < cnt; e += 256) {
    u64 k = buf[e];
    float f = __uint_as_float((u32)(k >> 32));
    int bin = (int)(f * 170.0f);
    bin = bin < 0 ? 0 : (bin > 1023 ? 1023 : bin);
    if (bin >= T) {
      float sc = 1.0f / (1.0f + expf(-f));   // f32 sigmoid, matches ref order
      u32 a = (u32)k;
      int pos = atomicAdd(&sNsel, 1);
      if (pos < SORTN)
        skey[pos] = ((u64)__float_as_uint(sc) << 32) | (0xFFFFFFFFu - a);
    }
  }
  __syncthreads();
  int nsel = sNsel;
  if (nsel > SORTN) nsel = SORTN;
  for (int i = tid; i < SORTN; i += 256)
    if (i >= nsel) skey[i] = 0;
  __syncthreads();

  // --- bitonic sort, descending (value desc, index asc via ~a) ---
  for (int k = 2; k <= SORTN; k <<= 1) {
    for (int j = k >> 1; j > 0; j >>= 1) {
      for (int t = tid; t < SORTN / 2; t += 256) {
        int i = ((t & ~(j - 1)) << 1) | (t & (j - 1));
        int ixj = i | j;
        u64 x = skey[i], y = skey[ixj];
        bool desc = ((i & k) == 0);
        if (desc ? (x < y) : (x > y)) { skey[i] = y; skey[ixj] = x; }
      }
      __syncthreads();
    }
  }

  // --- decode top-256 boxes (no-FMA f32 ops to mirror separate mul/add) ---
  {
    u64 k = skey[tid];
    float sc = __uint_as_float((u32)(k >> 32));
    u32 a = 0xFFFFFFFFu - (u32)k;
    int el = (k != 0ull) && (sc > 0.5f);
    if (!el || a >= NA) a = 0;   // padding guard (box masked out downstream)
    float4 p = ((const float4*)boxp)[(size_t)b * NA + a];
    float4 an = ((const float4*)anc)[a];
    float dx = __fmul_rn(p.x, 0.1f), dy = __fmul_rn(p.y, 0.1f);
    float dw = __fmul_rn(p.z, 0.2f), dh = __fmul_rn(p.w, 0.2f);
    float cx = __fadd_rn(__fmul_rn(dx, an.z), an.x);
    float cy = __fadd_rn(__fmul_rn(dy, an.w), an.y);
    float w = __fmul_rn(expf(dw), an.z);
    float h = __fmul_rn(expf(dh), an.w);
    float4 bx;
    bx.x = __fsub_rn(cx, __fmul_rn(0.5f, w));
    bx.y = __fsub_rn(cy, __fmul_rn(0.5f, h));
    bx.z = __fadd_rn(cx, __fmul_rn(0.5f, w));
    bx.w = __fadd_rn(cy, __fmul_rn(0.5f, h));
    sBox[tid] = bx;
    sElig[tid] = el;
    candBox[(size_t)bc * KC + tid] = bx;
  }
  __syncthreads();

  // --- greedy NMS on wave 0: lane ln owns candidates s*64+ln ---
  if (tid < 64) {
    const int ln = tid;
    float x1[4], y1[4], x2[4], y2[4], ar[4];
    int keep = 0;
#pragma unroll
    for (int s = 0; s < 4; s++) {
      int j = s * 64 + ln;
      float4 bj = sBox[j];
      x1[s] = bj.x; y1[s] = bj.y; x2[s] = bj.z; y2[s] = bj.w;
      ar[s] = __fmul_rn(__fsub_rn(bj.z, bj.x), __fsub_rn(bj.w, bj.y));
      if (sElig[j]) keep |= (1 << s);
    }
    for (int i = 0; i < KC; i++) {
      int ki = __shfl(keep, i & 63, 64);
      if ((ki >> (i >> 6)) & 1) {          // wave-uniform branch
        float4 bi = sBox[i];               // same-address LDS broadcast
        float ai = __fmul_rn(__fsub_rn(bi.z, bi.x), __fsub_rn(bi.w, bi.y));
#pragma unroll
        for (int s = 0; s < 4; s++) {
          int j = s * 64 + ln;
          if (j > i) {
            float lx = fmaxf(bi.x, x1[s]), ly = fmaxf(bi.y, y1[s]);
            float rx = fminf(bi.z, x2[s]), ry = fminf(bi.w, y2[s]);
            float wx = fmaxf(__fsub_rn(rx, lx), 0.0f);
            float wy = fmaxf(__fsub_rn(ry, ly), 0.0f);
            float inter = __fmul_rn(wx, wy);
            float uni = fmaxf(__fsub_rn(__fadd_rn(ai, ar[s]), inter), 1e-8f);
            float iou = __fdiv_rn(inter, uni);
            if (iou > 0.5f) keep &= ~(1 << s);
          }
        }
      }
    }
    // cap at MAXT kept (cumsum over pre-cap keep), compact in order
    u64 m[4];
#pragma unroll
    for (int s = 0; s < 4; s++) m[s] = __ballot((keep >> s) & 1);
    int tot = 0;
#pragma unroll
    for (int s = 0; s < 4; s++) tot += __popcll(m[s]);
    int keptTotal = tot < MAXT ? tot : MAXT;
    u64 lmask = (1ull << ln) - 1ull;
    int base = 0;
#pragma unroll
    for (int s = 0; s < 4; s++) {
      int j = s * 64 + ln;
      int cum = base + (int)__popcll(m[s] & lmask);
      if (((keep >> s) & 1) && cum < MAXT) {
        u64 hi = skey[j] >> 32;
        classList[(size_t)bc * KC + cum] =
            (hi << 32) | (u64)(0xFFFFFFFFu - (u32)(c * KC + j));
      }
      base += (int)__popcll(m[s]);
    }
    for (int t2 = ln; t2 < KC; t2 += 64)
      if (t2 >= keptTotal) classList[(size_t)bc * KC + t2] = 0;
  }
}

// ---------------------------------------------------------------------------
// Top-256 merge of two desc-sorted 256-lists: half-cleaner + bitonic clean.
// ---------------------------------------------------------------------------
__device__ __forceinline__ void merge_step(u64* acc, const u64* cur, int t) {
  u64 x = acc[t], y = cur[KC - 1 - t];
  acc[t] = x > y ? x : y;          // each thread touches only acc[t]
  __syncthreads();
  for (int s = 128; s >= 1; s >>= 1) {
    if (t < 128) {
      int i = ((t & ~(s - 1)) << 1) | (t & (s - 1));
      u64 a = acc[i], b = acc[i + s];
      if (a < b) { acc[i] = b; acc[i + s] = a; }
    }
    __syncthreads();
  }
}

__global__ __launch_bounds__(256) void kmerge1(const u64* __restrict__ classList,
                                               u64* __restrict__ c1) {
  __shared__ u64 acc[KC], cur[KC];
  int t = threadIdx.x;
  int b = blockIdx.x >> 3, g = blockIdx.x & 7;
  const u64* base = classList + (size_t)(b * NC + g * 10) * KC;
  acc[t] = base[t];
  __syncthreads();
  for (int m = 1; m < 10; m++) {
    cur[t] = base[(size_t)m * KC + t];
    __syncthreads();
    merge_step(acc, cur, t);
  }
  c1[(size_t)blockIdx.x * KC + t] = acc[t];
}

__global__ __launch_bounds__(256) void kmerge2(const u64* __restrict__ c1,
                                               const float4* __restrict__ candBox,
                                               float* __restrict__ out) {
  __shared__ u64 acc[KC], cur[KC];
  int t = threadIdx.x, b = blockIdx.x;
  const u64* base = c1 + (size_t)b * 8 * KC;
  acc[t] = base[t];
  __syncthreads();
  for (int m = 1; m < 8; m++) {
    cur[t] = base[(size_t)m * KC + t];
    __syncthreads();
    merge_step(acc, cur, t);
  }
  if (t < MAXT) {
    u64 k = acc[t];
    float4 bx = make_float4(0.f, 0.f, 0.f, 0.f);
    float sc = 0.0f, lb = -1.0f;
    if (k != 0ull) {
      sc = __uint_as_float((u32)(k >> 32));
      u32 flat = 0xFFFFFFFFu - (u32)k;
      int cc = (int)(flat >> 8), kk = (int)(flat & 255u);
      bx = candBox[((size_t)b * NC + cc) * KC + kk];
      lb = (float)cc;
    }
    float* ob = out + ((size_t)b * MAXT + t) * 4;
    ob[0] = bx.x; ob[1] = bx.y; ob[2] = bx.z; ob[3] = bx.w;
    out[NB * MAXT * 4 + b * MAXT + t] = sc;                 // scores @ 6400
    out[NB * MAXT * 4 + NB * MAXT + b * MAXT + t] = lb;     // labels @ 8000
  }
}

extern "C" void kernel_launch(void* const* d_in, const int* in_sizes, int n_in,
                              void* d_out, int out_size, void* d_ws,
                              size_t ws_size, hipStream_t stream) {
  const float* boxp = (const float*)d_in[0];   // [B,A,4]
  const float* cls = (const float*)d_in[1];    // [B,A,C]
  const float* anc = (const float*)d_in[2];    // [A,4]
  char* ws = (char*)d_ws;
  u64* bufA = (u64*)(ws + OFF_BUFA);
  u64* classList = (u64*)(ws + OFF_CLASSLIST);
  u64* c1 = (u64*)(ws + OFF_C1);
  float4* candBox = (float4*)(ws + OFF_CANDBOX);
  u32* counts = (u32*)(ws + OFF_COUNTS);

  hipMemsetAsync(counts, 0, NB * NC * CSTRIDE * sizeof(u32), stream);
  kfilter<<<NB * NCHUNK, 256, 0, stream>>>(cls, bufA, counts);
  kselect<<<NB * NC, 256, 0, stream>>>(cls, boxp, anc, bufA, counts, classList,
                                       candBox);
  kmerge1<<<NB * 8, 256, 0, stream>>>(classList, c1);
  kmerge2<<<NB, 256, 0, stream>>>(c1, candBox, (float*)d_out);
}

// Round 3
// 410.513 us; speedup vs baseline: 3.6118x; 1.0572x over previous
//
#include <hip/hip_runtime.h>
#include <math.h>
#include <stdint.h>

typedef unsigned long long u64;
typedef unsigned int u32;

#define NB 8
#define NA 76725
#define NC 80
#define KC 256
#define MAXT 200
#define CAP 2048
#define SORTN 512
#define TAU 2.0f
#define CHUNK 512
#define NCHUNK 150         // ceil(76725/512)
#define BCAP 48            // per-class per-chunk LDS bucket (exp ~11.6, 10 sigma)
#define CSTRIDE 16         // counts padded: one per 64B line

// Workspace layout (bytes). Total ~14.46 MB.
#define OFF_BUFA      0ull            // u64 [NB*NC*CAP]   10,485,760
#define OFF_CLASSLIST 10485760ull     // u64 [NB*NC*KC]     1,310,720
#define OFF_CANDBOX   11796480ull     // float4[NB*NC*KC]   2,621,440
#define OFF_COUNTS    14417920ull     // u32 [NB*NC*CSTRIDE]   40,960

// ---------------------------------------------------------------------------
// Kernel A: block owns a [512-anchor x 80-class] tile; logits > TAU go to
// per-class LDS buckets (unrolled x4 loads for MLP); one global atomicAdd
// per class per block reserves bufA range; cooperative flush.
// ---------------------------------------------------------------------------
__device__ __forceinline__ void kf_proc(float4 v, int i, int a0,
                                        u64 (*bucket)[BCAP], u32* bcnt) {
  int a = a0 + i / (NC / 4);
  int c0 = (i % (NC / 4)) * 4;
  float vv[4] = {v.x, v.y, v.z, v.w};
#pragma unroll
  for (int j = 0; j < 4; j++) {
    if (vv[j] > TAU) {
      int c = c0 + j;
      u32 pos = atomicAdd(&bcnt[c], 1u);
      if (pos < BCAP)
        bucket[c][pos] = ((u64)__float_as_uint(vv[j]) << 32) | (u32)a;
    }
  }
}

__global__ __launch_bounds__(256) void kfilter(const float* __restrict__ cls,
                                               u64* __restrict__ bufA,
                                               u32* __restrict__ counts) {
  __shared__ u64 bucket[NC][BCAP];   // 30 KB
  __shared__ u32 bcnt[NC];
  __shared__ u32 gbase[NC];
  __shared__ u32 pref[NC + 1];

  const int b = blockIdx.x / NCHUNK;
  const int ch = blockIdx.x % NCHUNK;
  const int tid = threadIdx.x;
  const int a0 = ch * CHUNK;
  const int aN = (NA - a0) < CHUNK ? (NA - a0) : CHUNK;

  for (int i = tid; i < NC; i += 256) bcnt[i] = 0;
  __syncthreads();

  const float4* p = (const float4*)(cls + ((size_t)b * NA + a0) * NC);
  const int n4 = aN * (NC / 4);
  for (int i0 = tid; i0 < n4; i0 += 1024) {
    float4 v0, v1, v2, v3;
    const bool g1 = i0 + 256 < n4, g2 = i0 + 512 < n4, g3 = i0 + 768 < n4;
    v0 = p[i0];                       // 4 independent loads in flight
    if (g1) v1 = p[i0 + 256];
    if (g2) v2 = p[i0 + 512];
    if (g3) v3 = p[i0 + 768];
    kf_proc(v0, i0, a0, bucket, bcnt);
    if (g1) kf_proc(v1, i0 + 256, a0, bucket, bcnt);
    if (g2) kf_proc(v2, i0 + 512, a0, bucket, bcnt);
    if (g3) kf_proc(v3, i0 + 768, a0, bucket, bcnt);
  }
  __syncthreads();
  if (tid < NC) {
    u32 n = bcnt[tid];
    if (n > BCAP) n = BCAP;
    bcnt[tid] = n;
    gbase[tid] = atomicAdd(&counts[(b * NC + tid) * CSTRIDE], n);
  }
  __syncthreads();
  if (tid == 0) {
    u32 s = 0;
    for (int c = 0; c < NC; c++) { pref[c] = s; s += bcnt[c]; }
    pref[NC] = s;
  }
  __syncthreads();
  const int total = (int)pref[NC];
  for (int e = tid; e < total; e += 256) {
    int lo = 0, hi = NC;
    while (lo + 1 < hi) { int mid = (lo + hi) >> 1; if ((int)pref[mid] <= e) lo = mid; else hi = mid; }
    int c = lo;
    int loc = e - (int)pref[c];
    u32 gb = gbase[c] + (u32)loc;
    if (gb < CAP)
      bufA[((size_t)(b * NC + c)) * CAP + gb] = bucket[c][loc];
  }
}

// ---------------------------------------------------------------------------
// Kernel B: per-(b,c). bufA -> LDS once; histogram top-~256; sort 512;
// decode; NMS with keep-independent suppression compute (pipelinable);
// cap 200; write kept list + candidate boxes.
// ---------------------------------------------------------------------------
__global__ __launch_bounds__(256) void kselect(
    const float* __restrict__ cls, const float* __restrict__ boxp,
    const float* __restrict__ anc, u64* __restrict__ bufA,
    const u32* __restrict__ counts, u64* __restrict__ classList,
    float4* __restrict__ candBox) {
  __shared__ u64 sbuf[CAP];          // 16 KB
  __shared__ u32 hist[1024];
  __shared__ int sbsum[64];
  __shared__ int sT, sNsel, sExtra;
  __shared__ u64 skey[SORTN];        // 4 KB
  __shared__ float4 sBox[KC];
  __shared__ float sAr[KC];

  const int tid = threadIdx.x;
  const int bc = blockIdx.x;
  const int b = bc / NC, c = bc % NC;
  u64* buf = bufA + (size_t)bc * CAP;

  int cnt0 = (int)counts[bc * CSTRIDE];
  if (cnt0 > CAP) cnt0 = CAP;
  int cnt = cnt0;
  if (cnt0 < KC) {
    // Fallback (never expected on this data): collect 0 < logit <= TAU too.
    if (tid == 0) sExtra = 0;
    __syncthreads();
    for (int a = tid; a < NA; a += 256) {
      float x = cls[((size_t)b * NA + a) * NC + c];
      if (x > 0.0f && !(x > TAU)) {
        int pos = cnt0 + atomicAdd(&sExtra, 1);
        if (pos < CAP) buf[pos] = ((u64)__float_as_uint(x) << 32) | (u32)a;
      }
    }
    __syncthreads();
    cnt = cnt0 + sExtra;
  }
  if (cnt > CAP) cnt = CAP;

  // --- single global pass: bufA -> LDS; zero hist meanwhile ---
  for (int i = tid; i < 1024; i += 256) hist[i] = 0;
  if (tid == 0) sNsel = 0;
  for (int e = tid; e < cnt; e += 256) sbuf[e] = buf[e];
  __syncthreads();

  // --- histogram over logit (bin width 1/170) ---
  for (int e = tid; e < cnt; e += 256) {
    float f = __uint_as_float((u32)(sbuf[e] >> 32));
    int bin = (int)(f * 170.0f);
    bin = bin < 0 ? 0 : (bin > 1023 ? 1023 : bin);
    atomicAdd(&hist[bin], 1u);
  }
  __syncthreads();
  if (tid < 64) {
    int s = 0;
    for (int i = 0; i < 16; i++) s += (int)hist[tid * 16 + i];
    sbsum[tid] = s;
  }
  __syncthreads();
  if (tid == 0) {
    int acc = 0, sb = 63;
    while (sb >= 0 && acc + sbsum[sb] < KC) { acc += sbsum[sb]; sb--; }
    int T = 0;
    if (sb >= 0) {
      int bin = sb * 16 + 15;
      while (bin > sb * 16 && acc + (int)hist[bin] < KC) {
        acc += (int)hist[bin];
        bin--;
      }
      T = bin;
    }
    sT = T;
  }
  __syncthreads();
  const int T = sT;

  // --- compact selected entries with final sort key ---
  for (int e = tid; e < cnt; e += 256) {
    u64 k = sbuf[e];
    float f = __uint_as_float((u32)(k >> 32));
    int bin = (int)(f * 170.0f);
    bin = bin < 0 ? 0 : (bin > 1023 ? 1023 : bin);
    if (bin >= T) {
      float sc = 1.0f / (1.0f + expf(-f));   // f32 sigmoid, matches ref order
      u32 a = (u32)k;
      int pos = atomicAdd(&sNsel, 1);
      if (pos < SORTN)
        skey[pos] = ((u64)__float_as_uint(sc) << 32) | (0xFFFFFFFFu - a);
    }
  }
  __syncthreads();
  int nsel = sNsel;
  if (nsel > SORTN) nsel = SORTN;
  for (int i = tid; i < SORTN; i += 256)
    if (i >= nsel) skey[i] = 0;
  __syncthreads();

  // --- bitonic sort 512, descending; 1 compare-exchange per thread per pass ---
  for (int k = 2; k <= SORTN; k <<= 1) {
    for (int j = k >> 1; j > 0; j >>= 1) {
      int i = ((tid & ~(j - 1)) << 1) | (tid & (j - 1));
      int ixj = i | j;
      u64 x = skey[i], y = skey[ixj];
      bool desc = ((i & k) == 0);
      if (desc ? (x < y) : (x > y)) { skey[i] = y; skey[ixj] = x; }
      __syncthreads();
    }
  }

  // --- decode top-256 boxes (no-FMA f32 ops to mirror separate mul/add) ---
  {
    u64 k = skey[tid];
    u32 a = 0xFFFFFFFFu - (u32)k;
    if (k == 0ull || a >= NA) a = 0;  // padding guard (never kept downstream)
    float4 p = ((const float4*)boxp)[(size_t)b * NA + a];
    float4 an = ((const float4*)anc)[a];
    float dx = __fmul_rn(p.x, 0.1f), dy = __fmul_rn(p.y, 0.1f);
    float dw = __fmul_rn(p.z, 0.2f), dh = __fmul_rn(p.w, 0.2f);
    float cx = __fadd_rn(__fmul_rn(dx, an.z), an.x);
    float cy = __fadd_rn(__fmul_rn(dy, an.w), an.y);
    float w = __fmul_rn(expf(dw), an.z);
    float h = __fmul_rn(expf(dh), an.w);
    float4 bx;
    bx.x = __fsub_rn(cx, __fmul_rn(0.5f, w));
    bx.y = __fsub_rn(cy, __fmul_rn(0.5f, h));
    bx.z = __fadd_rn(cx, __fmul_rn(0.5f, w));
    bx.w = __fadd_rn(cy, __fmul_rn(0.5f, h));
    sBox[tid] = bx;
    sAr[tid] = __fmul_rn(__fsub_rn(bx.z, bx.x), __fsub_rn(bx.w, bx.y));
    candBox[(size_t)bc * KC + tid] = bx;
  }
  __syncthreads();

  // --- greedy NMS on wave 0: lane ln owns candidates s*64+ln.
  //     Suppression compute is keep-independent -> compiler pipelines it;
  //     serial chain is just shfl+and. ---
  if (tid < 64) {
    const int ln = tid;
    float x1[4], y1[4], x2[4], y2[4], ar[4];
    int keep = 0;
#pragma unroll
    for (int s = 0; s < 4; s++) {
      int j = s * 64 + ln;
      float4 bj = sBox[j];
      x1[s] = bj.x; y1[s] = bj.y; x2[s] = bj.z; y2[s] = bj.w;
      ar[s] = sAr[j];
      if (skey[j] != 0ull) keep |= (1 << s);
    }
    for (int i = 0; i < KC; i++) {
      float4 bi = sBox[i];            // unconditional: pipelinable
      float ai = sAr[i];
      int sup = 0;
#pragma unroll
      for (int s = 0; s < 4; s++) {
        int j = s * 64 + ln;
        float lx = fmaxf(bi.x, x1[s]), ly = fmaxf(bi.y, y1[s]);
        float rx = fminf(bi.z, x2[s]), ry = fminf(bi.w, y2[s]);
        float wx = fmaxf(__fsub_rn(rx, lx), 0.0f);
        float wy = fmaxf(__fsub_rn(ry, ly), 0.0f);
        float inter = __fmul_rn(wx, wy);
        float uni = fmaxf(__fsub_rn(__fadd_rn(ai, ar[s]), inter), 1e-8f);
        float iou = __fdiv_rn(inter, uni);
        if (j > i && iou > 0.5f) sup |= (1 << s);
      }
      int ki = __shfl(keep, i & 63, 64);
      if ((ki >> (i >> 6)) & 1) keep &= ~sup;
    }
    // cap at MAXT kept (cumsum over pre-cap keep), compact in order
    u64 m[4];
#pragma unroll
    for (int s = 0; s < 4; s++) m[s] = __ballot((keep >> s) & 1);
    int tot = 0;
#pragma unroll
    for (int s = 0; s < 4; s++) tot += __popcll(m[s]);
    int keptTotal = tot < MAXT ? tot : MAXT;
    u64 lmask = (1ull << ln) - 1ull;
    int base = 0;
#pragma unroll
    for (int s = 0; s < 4; s++) {
      int j = s * 64 + ln;
      int cum = base + (int)__popcll(m[s] & lmask);
      if (((keep >> s) & 1) && cum < MAXT) {
        u64 hi = skey[j] >> 32;
        classList[(size_t)bc * KC + cum] =
            (hi << 32) | (u64)(0xFFFFFFFFu - (u32)(c * KC + j));
      }
      base += (int)__popcll(m[s]);
    }
    for (int t2 = ln; t2 < KC; t2 += 64)
      if (t2 >= keptTotal) classList[(size_t)bc * KC + t2] = 0;
  }
}

// ---------------------------------------------------------------------------
// Kernel C: single merge kernel, 8 blocks x 256. Wave-level tournament
// merge (regs + shfl, zero barriers in loops): each wave merges 20 class
// lists; wave 0 merges the 4 partials; threads emit top-200.
// Element i = reg*64 + lane.
// ---------------------------------------------------------------------------
__device__ __forceinline__ u64 shfl64(u64 v, int src) {
  int lo = __shfl((int)(u32)v, src, 64);
  int hi = __shfl((int)(v >> 32), src, 64);
  return ((u64)(u32)hi << 32) | (u32)lo;
}
__device__ __forceinline__ u64 shflxor64(u64 v, int mask) {
  int lo = __shfl_xor((int)(u32)v, mask, 64);
  int hi = __shfl_xor((int)(v >> 32), mask, 64);
  return ((u64)(u32)hi << 32) | (u32)lo;
}
#define CSWAP(a, b) { if ((a) < (b)) { u64 _t = (a); (a) = (b); (b) = _t; } }

__device__ __forceinline__ void wave_merge(u64 acc[4], const u64 cur[4], int ln) {
  // tournament: acc[i] = max(acc[i], cur[255-i]); 255-i = (3-r)*64 + (63-ln)
  u64 t0 = shfl64(cur[3], 63 - ln);
  u64 t1 = shfl64(cur[2], 63 - ln);
  u64 t2 = shfl64(cur[1], 63 - ln);
  u64 t3 = shfl64(cur[0], 63 - ln);
  acc[0] = acc[0] > t0 ? acc[0] : t0;
  acc[1] = acc[1] > t1 ? acc[1] : t1;
  acc[2] = acc[2] > t2 ? acc[2] : t2;
  acc[3] = acc[3] > t3 ? acc[3] : t3;
  // bitonic clean, descending. s=128: regs (0,2),(1,3); s=64: (0,1),(2,3)
  CSWAP(acc[0], acc[2]); CSWAP(acc[1], acc[3]);
  CSWAP(acc[0], acc[1]); CSWAP(acc[2], acc[3]);
#pragma unroll
  for (int s = 32; s >= 1; s >>= 1) {
#pragma unroll
    for (int k = 0; k < 4; k++) {
      u64 o = shflxor64(acc[k], s);
      u64 mx = acc[k] > o ? acc[k] : o;
      u64 mn = acc[k] < o ? acc[k] : o;
      acc[k] = ((ln & s) == 0) ? mx : mn;
    }
  }
}

__global__ __launch_bounds__(256) void kmerge(const u64* __restrict__ classList,
                                              const float4* __restrict__ candBox,
                                              float* __restrict__ out) {
  __shared__ u64 lds[4 * KC];
  const int tid = threadIdx.x, b = blockIdx.x;
  const int w = tid >> 6, ln = tid & 63;
  const u64* base = classList + ((size_t)b * NC + w * 20) * KC;
  u64 acc[4];
#pragma unroll
  for (int k = 0; k < 4; k++) acc[k] = base[k * 64 + ln];
  for (int m = 1; m < 20; m++) {
    u64 cur[4];
#pragma unroll
    for (int k = 0; k < 4; k++) cur[k] = base[(size_t)m * KC + k * 64 + ln];
    wave_merge(acc, cur, ln);
  }
#pragma unroll
  for (int k = 0; k < 4; k++) lds[w * KC + k * 64 + ln] = acc[k];
  __syncthreads();
  if (w == 0) {
    for (int m = 1; m < 4; m++) {
      u64 cur[4];
#pragma unroll
      for (int k = 0; k < 4; k++) cur[k] = lds[m * KC + k * 64 + ln];
      wave_merge(acc, cur, ln);
    }
#pragma unroll
    for (int k = 0; k < 4; k++) lds[k * 64 + ln] = acc[k];
  }
  __syncthreads();
  if (tid < MAXT) {
    u64 k = lds[tid];
    float4 bx = make_float4(0.f, 0.f, 0.f, 0.f);
    float sc = 0.0f, lb = -1.0f;
    if (k != 0ull) {
      sc = __uint_as_float((u32)(k >> 32));
      u32 flat = 0xFFFFFFFFu - (u32)k;
      int cc = (int)(flat >> 8), kk = (int)(flat & 255u);
      bx = candBox[((size_t)b * NC + cc) * KC + kk];
      lb = (float)cc;
    }
    float* ob = out + ((size_t)b * MAXT + tid) * 4;
    ob[0] = bx.x; ob[1] = bx.y; ob[2] = bx.z; ob[3] = bx.w;
    out[NB * MAXT * 4 + b * MAXT + tid] = sc;               // scores @ 6400
    out[NB * MAXT * 4 + NB * MAXT + b * MAXT + tid] = lb;   // labels @ 8000
  }
}

extern "C" void kernel_launch(void* const* d_in, const int* in_sizes, int n_in,
                              void* d_out, int out_size, void* d_ws,
                              size_t ws_size, hipStream_t stream) {
  const float* boxp = (const float*)d_in[0];   // [B,A,4]
  const float* cls = (const float*)d_in[1];    // [B,A,C]
  const float* anc = (const float*)d_in[2];    // [A,4]
  char* ws = (char*)d_ws;
  u64* bufA = (u64*)(ws + OFF_BUFA);
  u64* classList = (u64*)(ws + OFF_CLASSLIST);
  float4* candBox = (float4*)(ws + OFF_CANDBOX);
  u32* counts = (u32*)(ws + OFF_COUNTS);

  hipMemsetAsync(counts, 0, NB * NC * CSTRIDE * sizeof(u32), stream);
  kfilter<<<NB * NCHUNK, 256, 0, stream>>>(cls, bufA, counts);
  kselect<<<NB * NC, 256, 0, stream>>>(cls, boxp, anc, bufA, counts, classList,
                                       candBox);
  kmerge<<<NB, 256, 0, stream>>>(classList, candBox, (float*)d_out);
}

// Round 4
// 390.211 us; speedup vs baseline: 3.7997x; 1.0520x over previous
//
#include <hip/hip_runtime.h>
#include <math.h>
#include <stdint.h>

typedef unsigned long long u64;
typedef unsigned int u32;

#define NB 8
#define NA 76725
#define NC 80
#define KC 256
#define MAXT 200
#define CAP 2048
#define SELCAP 768
#define TAU 2.0f
#define CHUNK 512
#define NCHUNK 150         // ceil(76725/512)
#define BCAP 48            // per-class per-chunk LDS bucket (exp ~11.6, 10 sigma)
#define CSTRIDE 16         // counts padded: one per 64B line

// Workspace layout (bytes). Total ~14.46 MB.
#define OFF_BUFA      0ull            // u64 [NB*NC*CAP]   10,485,760
#define OFF_CLASSLIST 10485760ull     // u64 [NB*NC*KC]     1,310,720
#define OFF_CANDBOX   11796480ull     // float4[NB*NC*KC]   2,621,440
#define OFF_COUNTS    14417920ull     // u32 [NB*NC*CSTRIDE]   40,960

// ---------------------------------------------------------------------------
// Kernel A: block owns a [512-anchor x 80-class] tile; logits > TAU go to
// per-class LDS buckets (unrolled x8 loads for MLP); one global atomicAdd
// per class per block reserves bufA range; cooperative flush.
// ---------------------------------------------------------------------------
__device__ __forceinline__ void kf_proc(float4 v, int i, int a0,
                                        u64 (*bucket)[BCAP], u32* bcnt) {
  int a = a0 + i / (NC / 4);
  int c0 = (i % (NC / 4)) * 4;
  float vv[4] = {v.x, v.y, v.z, v.w};
#pragma unroll
  for (int j = 0; j < 4; j++) {
    if (vv[j] > TAU) {
      int c = c0 + j;
      u32 pos = atomicAdd(&bcnt[c], 1u);
      if (pos < BCAP)
        bucket[c][pos] = ((u64)__float_as_uint(vv[j]) << 32) | (u32)a;
    }
  }
}

__global__ __launch_bounds__(256) void kfilter(const float* __restrict__ cls,
                                               u64* __restrict__ bufA,
                                               u32* __restrict__ counts) {
  __shared__ u64 bucket[NC][BCAP];   // 30 KB
  __shared__ u32 bcnt[NC];
  __shared__ u32 gbase[NC];
  __shared__ u32 pref[NC + 1];

  const int b = blockIdx.x / NCHUNK;
  const int ch = blockIdx.x % NCHUNK;
  const int tid = threadIdx.x;
  const int a0 = ch * CHUNK;
  const int aN = (NA - a0) < CHUNK ? (NA - a0) : CHUNK;

  for (int i = tid; i < NC; i += 256) bcnt[i] = 0;
  __syncthreads();

  const float4* p = (const float4*)(cls + ((size_t)b * NA + a0) * NC);
  const int n4 = aN * (NC / 4);
  for (int i0 = tid; i0 < n4; i0 += 2048) {
    float4 v[8];
    bool g[8];
#pragma unroll
    for (int u = 0; u < 8; u++) {
      g[u] = (i0 + u * 256) < n4;
      if (g[u]) v[u] = p[i0 + u * 256];   // 8 independent loads in flight
    }
#pragma unroll
    for (int u = 0; u < 8; u++)
      if (g[u]) kf_proc(v[u], i0 + u * 256, a0, bucket, bcnt);
  }
  __syncthreads();
  if (tid < NC) {
    u32 n = bcnt[tid];
    if (n > BCAP) n = BCAP;
    bcnt[tid] = n;
    gbase[tid] = atomicAdd(&counts[(b * NC + tid) * CSTRIDE], n);
  }
  __syncthreads();
  if (tid == 0) {
    u32 s = 0;
    for (int c = 0; c < NC; c++) { pref[c] = s; s += bcnt[c]; }
    pref[NC] = s;
  }
  __syncthreads();
  const int total = (int)pref[NC];
  for (int e = tid; e < total; e += 256) {
    int lo = 0, hi = NC;
    while (lo + 1 < hi) { int mid = (lo + hi) >> 1; if ((int)pref[mid] <= e) lo = mid; else hi = mid; }
    int c = lo;
    int loc = e - (int)pref[c];
    u32 gb = gbase[c] + (u32)loc;
    if (gb < CAP)
      bufA[((size_t)(b * NC + c)) * CAP + gb] = bucket[c][loc];
  }
}

// ---------------------------------------------------------------------------
// Kernel B: per-(b,c). bufA -> LDS; superbin threshold (wave-parallel scan);
// rank-sort top-256 (O(n^2/p), broadcast reads); decode; suppression
// bit-matrix built by all 256 threads; wave-0 bit sweep; cap 200.
// ---------------------------------------------------------------------------
__global__ __launch_bounds__(256) void kselect(
    const float* __restrict__ cls, const float* __restrict__ boxp,
    const float* __restrict__ anc, u64* __restrict__ bufA,
    const u32* __restrict__ counts, u64* __restrict__ classList,
    float4* __restrict__ candBox) {
  __shared__ u64 sbuf[CAP];          // 16 KB
  __shared__ u32 hist[1024];         // 4 KB
  __shared__ u64 sel[SELCAP];        // 6 KB
  __shared__ u64 skey[KC];           // 2 KB
  __shared__ u64 scolT[4][KC];       // 8 KB  (suppression cols, transposed)
  __shared__ float4 sBox[KC];        // 4 KB
  __shared__ float sAr[KC];          // 1 KB
  __shared__ int sNsel, sExtra, sSb;

  const int tid = threadIdx.x;
  const int bc = blockIdx.x;
  const int b = bc / NC, c = bc % NC;
  u64* buf = bufA + (size_t)bc * CAP;

  int cnt0 = (int)counts[bc * CSTRIDE];
  if (cnt0 > CAP) cnt0 = CAP;
  int cnt = cnt0;
  if (cnt0 < KC) {
    // Fallback (never expected on this data): collect 0 < logit <= TAU too.
    if (tid == 0) sExtra = 0;
    __syncthreads();
    for (int a = tid; a < NA; a += 256) {
      float x = cls[((size_t)b * NA + a) * NC + c];
      if (x > 0.0f && !(x > TAU)) {
        int pos = cnt0 + atomicAdd(&sExtra, 1);
        if (pos < CAP) buf[pos] = ((u64)__float_as_uint(x) << 32) | (u32)a;
      }
    }
    __syncthreads();
    cnt = cnt0 + sExtra;
  }
  if (cnt > CAP) cnt = CAP;

  // --- single global pass -> LDS; init hist/skey meanwhile ---
  for (int i = tid; i < 1024; i += 256) hist[i] = 0;
  if (tid == 0) sNsel = 0;
  skey[tid] = 0;
  for (int e = tid; e < cnt; e += 256) sbuf[e] = buf[e];
  __syncthreads();

  // --- histogram over logit (bin width 1/170) ---
  for (int e = tid; e < cnt; e += 256) {
    float f = __uint_as_float((u32)(sbuf[e] >> 32));
    int bin = (int)(f * 170.0f);
    bin = bin < 0 ? 0 : (bin > 1023 ? 1023 : bin);
    atomicAdd(&hist[bin], 1u);
  }
  __syncthreads();

  // --- superbin (16-bin) threshold via wave-0 suffix scan + ballot ---
  if (tid < 64) {
    int s = 0;
#pragma unroll
    for (int i = 0; i < 16; i++) s += (int)hist[tid * 16 + i];
    int suf = s;
#pragma unroll
    for (int d = 1; d < 64; d <<= 1) {
      int t = __shfl_down(suf, d, 64);
      if (tid + d < 64) suf += t;
    }
    u64 mask = __ballot(suf >= KC);
    int sb = mask ? (63 - __clzll((long long)mask)) : 0;
    if (tid == 0) sSb = sb;
  }
  __syncthreads();
  const int sb = sSb;

  // --- compact entries in superbins >= sb with final sort key ---
  for (int e = tid; e < cnt; e += 256) {
    u64 k = sbuf[e];
    float f = __uint_as_float((u32)(k >> 32));
    int bin = (int)(f * 170.0f);
    bin = bin < 0 ? 0 : (bin > 1023 ? 1023 : bin);
    if ((bin >> 4) >= sb) {
      float sc = 1.0f / (1.0f + expf(-f));   // f32 sigmoid, matches ref order
      u32 a = (u32)k;
      int pos = atomicAdd(&sNsel, 1);
      if (pos < SELCAP)
        sel[pos] = ((u64)__float_as_uint(sc) << 32) | (0xFFFFFFFFu - a);
    }
  }
  __syncthreads();
  int nsel = sNsel;
  if (nsel > SELCAP) nsel = SELCAP;

  // --- rank-sort: keys distinct; rank = #{larger}; write skey[rank] ---
  for (int e = tid; e < nsel; e += 256) {
    u64 k = sel[e];
    int r = 0;
    for (int q = 0; q < nsel; q++) r += (sel[q] > k) ? 1 : 0;
    if (r < KC) skey[r] = k;
  }
  __syncthreads();

  // --- decode top-256 boxes (no-FMA f32 ops to mirror separate mul/add) ---
  {
    u64 k = skey[tid];
    u32 a = 0xFFFFFFFFu - (u32)k;
    if (k == 0ull || a >= NA) a = 0;  // padding guard (never kept downstream)
    float4 p = ((const float4*)boxp)[(size_t)b * NA + a];
    float4 an = ((const float4*)anc)[a];
    float dx = __fmul_rn(p.x, 0.1f), dy = __fmul_rn(p.y, 0.1f);
    float dw = __fmul_rn(p.z, 0.2f), dh = __fmul_rn(p.w, 0.2f);
    float cx = __fadd_rn(__fmul_rn(dx, an.z), an.x);
    float cy = __fadd_rn(__fmul_rn(dy, an.w), an.y);
    float w = __fmul_rn(expf(dw), an.z);
    float h = __fmul_rn(expf(dh), an.w);
    float4 bx;
    bx.x = __fsub_rn(cx, __fmul_rn(0.5f, w));
    bx.y = __fsub_rn(cy, __fmul_rn(0.5f, h));
    bx.z = __fadd_rn(cx, __fmul_rn(0.5f, w));
    bx.w = __fadd_rn(cy, __fmul_rn(0.5f, h));
    sBox[tid] = bx;
    sAr[tid] = __fmul_rn(__fsub_rn(bx.z, bx.x), __fsub_rn(bx.w, bx.y));
    candBox[(size_t)bc * KC + tid] = bx;
  }
  __syncthreads();

  // --- suppression matrix: thread j computes column j (bits i < j) ---
  {
    const int j = tid;
    float4 bj = sBox[j];
    float aj = sAr[j];
    u64 cw[4] = {0ull, 0ull, 0ull, 0ull};
    for (int i = 0; i < j; i++) {
      float4 bi = sBox[i];              // same-address broadcast
      float ai = sAr[i];
      float lx = fmaxf(bi.x, bj.x), ly = fmaxf(bi.y, bj.y);
      float rx = fminf(bi.z, bj.z), ry = fminf(bi.w, bj.w);
      float wx = fmaxf(__fsub_rn(rx, lx), 0.0f);
      float wy = fmaxf(__fsub_rn(ry, ly), 0.0f);
      float inter = __fmul_rn(wx, wy);
      float uni = fmaxf(__fsub_rn(__fadd_rn(ai, aj), inter), 1e-8f);
      float iou = __fdiv_rn(inter, uni);
      if (iou > 0.5f) cw[i >> 6] |= (1ull << (i & 63));
    }
#pragma unroll
    for (int w = 0; w < 4; w++) scolT[w][j] = cw[w];
  }
  __syncthreads();

  // --- greedy sweep on wave 0: lane ln owns j in {ln,64+ln,128+ln,192+ln};
  //     serial chain is shfl + bit ops only ---
  if (tid < 64) {
    const int ln = tid;
    u64 C[4][4];                        // C[s][w]: col of j=s*64+ln, word w
#pragma unroll
    for (int s = 0; s < 4; s++)
#pragma unroll
      for (int w = 0; w < 4; w++) C[s][w] = scolT[w][s * 64 + ln];
    int keep = 0;
#pragma unroll
    for (int s = 0; s < 4; s++)
      if (skey[s * 64 + ln] != 0ull) keep |= (1 << s);
#pragma unroll
    for (int w = 0; w < 4; w++) {
      u64 c0 = C[0][w], c1 = C[1][w], c2 = C[2][w], c3 = C[3][w];
      for (int t = 0; t < 64; t++) {     // i = w*64 + t, ascending
        int kt = __shfl(keep, t, 64);
        if ((kt >> w) & 1) {
          int sup = (int)((c0 >> t) & 1) | ((int)((c1 >> t) & 1) << 1) |
                    ((int)((c2 >> t) & 1) << 2) | ((int)((c3 >> t) & 1) << 3);
          keep &= ~sup;
        }
      }
    }
    // cap at MAXT kept (cumsum over pre-cap keep), compact in order
    u64 m[4];
#pragma unroll
    for (int s = 0; s < 4; s++) m[s] = __ballot((keep >> s) & 1);
    int tot = 0;
#pragma unroll
    for (int s = 0; s < 4; s++) tot += __popcll(m[s]);
    int keptTotal = tot < MAXT ? tot : MAXT;
    u64 lmask = (1ull << ln) - 1ull;
    int base = 0;
#pragma unroll
    for (int s = 0; s < 4; s++) {
      int j = s * 64 + ln;
      int cum = base + (int)__popcll(m[s] & lmask);
      if (((keep >> s) & 1) && cum < MAXT) {
        u64 hi = skey[j] >> 32;
        classList[(size_t)bc * KC + cum] =
            (hi << 32) | (u64)(0xFFFFFFFFu - (u32)(c * KC + j));
      }
      base += (int)__popcll(m[s]);
    }
    for (int t2 = ln; t2 < KC; t2 += 64)
      if (t2 >= keptTotal) classList[(size_t)bc * KC + t2] = 0;
  }
}

// ---------------------------------------------------------------------------
// Kernel C: single merge kernel, 8 blocks x 256. Wave-level tournament
// merge (regs + shfl, zero barriers in loops).
// ---------------------------------------------------------------------------
__device__ __forceinline__ u64 shfl64(u64 v, int src) {
  int lo = __shfl((int)(u32)v, src, 64);
  int hi = __shfl((int)(v >> 32), src, 64);
  return ((u64)(u32)hi << 32) | (u32)lo;
}
__device__ __forceinline__ u64 shflxor64(u64 v, int mask) {
  int lo = __shfl_xor((int)(u32)v, mask, 64);
  int hi = __shfl_xor((int)(v >> 32), mask, 64);
  return ((u64)(u32)hi << 32) | (u32)lo;
}
#define CSWAP(a, b) { if ((a) < (b)) { u64 _t = (a); (a) = (b); (b) = _t; } }

__device__ __forceinline__ void wave_merge(u64 acc[4], const u64 cur[4], int ln) {
  u64 t0 = shfl64(cur[3], 63 - ln);
  u64 t1 = shfl64(cur[2], 63 - ln);
  u64 t2 = shfl64(cur[1], 63 - ln);
  u64 t3 = shfl64(cur[0], 63 - ln);
  acc[0] = acc[0] > t0 ? acc[0] : t0;
  acc[1] = acc[1] > t1 ? acc[1] : t1;
  acc[2] = acc[2] > t2 ? acc[2] : t2;
  acc[3] = acc[3] > t3 ? acc[3] : t3;
  CSWAP(acc[0], acc[2]); CSWAP(acc[1], acc[3]);
  CSWAP(acc[0], acc[1]); CSWAP(acc[2], acc[3]);
#pragma unroll
  for (int s = 32; s >= 1; s >>= 1) {
#pragma unroll
    for (int k = 0; k < 4; k++) {
      u64 o = shflxor64(acc[k], s);
      u64 mx = acc[k] > o ? acc[k] : o;
      u64 mn = acc[k] < o ? acc[k] : o;
      acc[k] = ((ln & s) == 0) ? mx : mn;
    }
  }
}

__global__ __launch_bounds__(256) void kmerge(const u64* __restrict__ classList,
                                              const float4* __restrict__ candBox,
                                              float* __restrict__ out) {
  __shared__ u64 lds[4 * KC];
  const int tid = threadIdx.x, b = blockIdx.x;
  const int w = tid >> 6, ln = tid & 63;
  const u64* base = classList + ((size_t)b * NC + w * 20) * KC;
  u64 acc[4];
#pragma unroll
  for (int k = 0; k < 4; k++) acc[k] = base[k * 64 + ln];
  for (int m = 1; m < 20; m++) {
    u64 cur[4];
#pragma unroll
    for (int k = 0; k < 4; k++) cur[k] = base[(size_t)m * KC + k * 64 + ln];
    wave_merge(acc, cur, ln);
  }
#pragma unroll
  for (int k = 0; k < 4; k++) lds[w * KC + k * 64 + ln] = acc[k];
  __syncthreads();
  if (w == 0) {
    for (int m = 1; m < 4; m++) {
      u64 cur[4];
#pragma unroll
      for (int k = 0; k < 4; k++) cur[k] = lds[m * KC + k * 64 + ln];
      wave_merge(acc, cur, ln);
    }
#pragma unroll
    for (int k = 0; k < 4; k++) lds[k * 64 + ln] = acc[k];
  }
  __syncthreads();
  if (tid < MAXT) {
    u64 k = lds[tid];
    float4 bx = make_float4(0.f, 0.f, 0.f, 0.f);
    float sc = 0.0f, lb = -1.0f;
    if (k != 0ull) {
      sc = __uint_as_float((u32)(k >> 32));
      u32 flat = 0xFFFFFFFFu - (u32)k;
      int cc = (int)(flat >> 8), kk = (int)(flat & 255u);
      bx = candBox[((size_t)b * NC + cc) * KC + kk];
      lb = (float)cc;
    }
    float* ob = out + ((size_t)b * MAXT + tid) * 4;
    ob[0] = bx.x; ob[1] = bx.y; ob[2] = bx.z; ob[3] = bx.w;
    out[NB * MAXT * 4 + b * MAXT + tid] = sc;               // scores @ 6400
    out[NB * MAXT * 4 + NB * MAXT + b * MAXT + tid] = lb;   // labels @ 8000
  }
}

extern "C" void kernel_launch(void* const* d_in, const int* in_sizes, int n_in,
                              void* d_out, int out_size, void* d_ws,
                              size_t ws_size, hipStream_t stream) {
  const float* boxp = (const float*)d_in[0];   // [B,A,4]
  const float* cls = (const float*)d_in[1];    // [B,A,C]
  const float* anc = (const float*)d_in[2];    // [A,4]
  char* ws = (char*)d_ws;
  u64* bufA = (u64*)(ws + OFF_BUFA);
  u64* classList = (u64*)(ws + OFF_CLASSLIST);
  float4* candBox = (float4*)(ws + OFF_CANDBOX);
  u32* counts = (u32*)(ws + OFF_COUNTS);

  hipMemsetAsync(counts, 0, NB * NC * CSTRIDE * sizeof(u32), stream);
  kfilter<<<NB * NCHUNK, 256, 0, stream>>>(cls, bufA, counts);
  kselect<<<NB * NC, 256, 0, stream>>>(cls, boxp, anc, bufA, counts, classList,
                                       candBox);
  kmerge<<<NB, 256, 0, stream>>>(classList, candBox, (float*)d_out);
}